// Round 7
// baseline (28488.513 us; speedup 1.0000x reference)
//
#include <hip/hip_runtime.h>

typedef float v2f __attribute__((ext_vector_type(2)));
typedef float v4f __attribute__((ext_vector_type(4)));

#define T_STEPS 100000
#define UDIM 7
#define NCHUNK 1562   /* full 64-step chunks */
#define TAIL 32       /* 100000 - 1562*64 */
#define ZSTR 68       /* zhist row stride (floats) */
#define ZH (64 * ZSTR)
#define UROWS 65      /* 64 steps + duplicated row0 of next chunk */
#define UAB (UROWS * 64)

__device__ __forceinline__ float tanh_fast(float x) {
    float e = __expf(2.0f * x);
    return 1.0f - 2.0f * __builtin_amdgcn_rcpf(e + 1.0f);
}

__device__ __forceinline__ float readlane_f(float v, int l) {
    return __int_as_float(__builtin_amdgcn_readlane(__float_as_int(v), l));
}

template <int CTRL>
__device__ __forceinline__ float dpp_f(float v) {
    return __int_as_float(__builtin_amdgcn_update_dpp(
        0, __float_as_int(v), CTRL, 0xF, 0xF, true));
}

/* Fused same-wave broadcast: ds_write + 4x ds_read_b128 with NO intermediate
   s_waitcnt (DS unit processes same-wave DS ops in order); single drain at end.
   waddr/raddr are LDS byte offsets (low 32 bits of the generic address). */
__device__ __forceinline__ void lds_bcast16(unsigned waddr, float val, unsigned raddr,
                                            v4f& r0, v4f& r1, v4f& r2, v4f& r3) {
    asm volatile(
        "ds_write_b32 %4, %5\n\t"
        "ds_read_b128 %0, %6\n\t"
        "ds_read_b128 %1, %6 offset:16\n\t"
        "ds_read_b128 %2, %6 offset:32\n\t"
        "ds_read_b128 %3, %6 offset:48\n\t"
        "s_waitcnt lgkmcnt(0)"
        : "=&v"(r0), "=&v"(r1), "=&v"(r2), "=&v"(r3)
        : "v"(waddr), "v"(val), "v"(raddr)
        : "memory");
}

__global__ __launch_bounds__(128) __attribute__((amdgpu_waves_per_eu(1, 1)))
void node_scan(const float* __restrict__ U,
               const float* __restrict__ W1, const float* __restrict__ b1,
               const float* __restrict__ W2, const float* __restrict__ b2,
               const float* __restrict__ W3, const float* __restrict__ b3,
               const float* __restrict__ wd, const float* __restrict__ bd,
               const float* __restrict__ wt, const float* __restrict__ bt,
               const float* __restrict__ wc, const float* __restrict__ bc,
               const float* __restrict__ h0,
               float* __restrict__ out)
{
    const int tid  = threadIdx.x;
    const int wv   = tid >> 6;               // 0 = compute wave, 1 = service wave
    const int lane = tid & 63;
    const int g = lane >> 2;                 // output group (0..15)
    const int q = lane & 3;                  // z-segment this lane reads (0..3)
    const float dt = (float)(5.0 / 60.0);

    __shared__ __align__(16) float zbuf[64];          // z1 broadcast / vacc scatter
    __shared__ __align__(16) float ubuf[3 * 512];     // u chunks (wave1-only)
    __shared__ __align__(16) float zhist[2 * ZH];     // z2 history, double-buffered
    __shared__ __align__(16) float cbuf[3 * 64];      // readout functionals (wave1)
    __shared__ __align__(16) float uab[2 * UAB];      // uacc tables, double-buffered
    __shared__ __align__(16) float Msh[64 * 64];      // M staging (init only)
    __shared__ int flg[4];                            // 0=w0 done,1=uacc ready,2=batch done

    if (tid == 0) { flg[0] = 0; flg[1] = 0; flg[2] = 0; }

    // wave0 regs
    float w1h[16]; float b2r = 0.f;
    v2f W2p[4][8];
    // wave1 regs
    v2f W1up[3]; float W1u6 = 0.f, b1l = 0.f;
    float rbD = 0.f, rbT = 0.f, rbC = 0.f, rchD = 0.f, rchT = 0.f, rchC = 0.f;

    if (wv == 0) {
#pragma unroll
        for (int j = 0; j < 16; ++j) w1h[j] = W1[lane * 23 + j];
        b2r = b2[lane];
#pragma unroll
        for (int d = 0; d < 4; ++d) {
            const int orow = (g << 2) | (q ^ d);
            const float* w2r = W2 + orow * 64 + q * 16;
#pragma unroll
            for (int j = 0; j < 8; ++j) W2p[d][j] = (v2f){ w2r[2 * j], w2r[2 * j + 1] };
        }
        for (int c = 0; c < 64; ++c) {
            float acc = 0.f;
#pragma unroll
            for (int k = 0; k < 16; ++k) acc = fmaf(w1h[k], W3[k * 64 + c], acc);
            Msh[lane * 64 + c] = acc;
        }
    } else {
        // u-part weights for this lane's row
#pragma unroll
        for (int j = 0; j < 3; ++j) {
            W1up[j].x = W1[lane * 23 + 16 + 2 * j];
            W1up[j].y = W1[lane * 23 + 17 + 2 * j];
        }
        W1u6 = W1[lane * 23 + 22];
        b1l = b1[lane];
        // readout functionals c = W3^T w → LDS
        float cd = 0.f, ct = 0.f, cc = 0.f;
        for (int k = 0; k < 16; ++k) {
            const float w3v = W3[k * 64 + lane];
            cd = fmaf(wd[k], w3v, cd);
            ct = fmaf(wt[k], w3v, ct);
            cc = fmaf(wc[k], w3v, cc);
        }
        cbuf[lane] = cd; cbuf[64 + lane] = ct; cbuf[128 + lane] = cc;
        rchD = bd[0]; rchT = bt[0]; rchC = bc[0];
        for (int k = 0; k < 16; ++k) {
            rbD = fmaf(wd[k], b3[k], rbD);  rchD = fmaf(wd[k], h0[k], rchD);
            rbT = fmaf(wt[k], b3[k], rbT);  rchT = fmaf(wt[k], h0[k], rchT);
            rbC = fmaf(wc[k], b3[k], rbC);  rchC = fmaf(wc[k], h0[k], rchC);
        }
        rbD *= dt; rbT *= dt; rbC *= dt;
        // stage u chunks 0,1,2
#pragma unroll
        for (int c = 0; c < 3; ++c) {
            const int base = c * 448, dst = c * 512;
#pragma unroll
            for (int r = 0; r < UDIM; ++r) {
                int flat = r * 64 + lane;
                int s = flat / 7, cc2 = flat % 7;
                ubuf[dst + s * 8 + cc2] = U[base + flat];
            }
            ubuf[dst + lane * 8 + 7] = 0.f;
        }
    }
    __syncthreads();

    if (wv == 0) {
        v2f Mp[4][8];
#pragma unroll
        for (int d = 0; d < 4; ++d) {
            const int orow = (g << 2) | (q ^ d);
            const float* mr = Msh + orow * 64 + q * 16;
#pragma unroll
            for (int j = 0; j < 8; ++j) Mp[d][j] = (v2f){ mr[2 * j], mr[2 * j + 1] };
        }
        float m3od = 0.f;
#pragma unroll
        for (int k = 0; k < 16; ++k) m3od = fmaf(w1h[k], b3[k], m3od);
        float A = 0.f;
        for (int k = 0; k < 16; ++k) A = fmaf(w1h[k], h0[k], A);

        // LDS byte offsets (low 32 bits of generic address = LDS offset)
        const unsigned zb_w = (unsigned)(uintptr_t)&zbuf[lane];
        const unsigned zb_r = (unsigned)(uintptr_t)&zbuf[q * 16];

        while (__hip_atomic_load(&flg[1], __ATOMIC_ACQUIRE,
                                 __HIP_MEMORY_SCOPE_WORKGROUP) < 1)
            __builtin_amdgcn_s_sleep(1);
        float uacc = uab[lane];                        // chunk0 row0

        auto step = [&](int li, int ub4, int zb4) {
            const float z1 = tanh_fast(A + uacc);
            v4f s0, s1, s2, s3;
            lds_bcast16(zb_w, z1, zb_r, s0, s1, s2, s3);
            const float uacc_next = uab[ub4 + (li + 1) * 64 + lane];

            v2f e0 = {s0.x, s0.y}, e1 = {s0.z, s0.w};
            v2f e2 = {s1.x, s1.y}, e3 = {s1.z, s1.w};
            v2f e4 = {s2.x, s2.y}, e5 = {s2.z, s2.w};
            v2f e6 = {s3.x, s3.y}, e7 = {s3.z, s3.w};
            v2f c0 = {b2r, 0.f}, c1 = {0.f, 0.f}, c2 = {0.f, 0.f}, c3 = {0.f, 0.f};
            c0 = __builtin_elementwise_fma(W2p[0][0], e0, c0);
            c1 = __builtin_elementwise_fma(W2p[1][0], e0, c1);
            c2 = __builtin_elementwise_fma(W2p[2][0], e0, c2);
            c3 = __builtin_elementwise_fma(W2p[3][0], e0, c3);
            c0 = __builtin_elementwise_fma(W2p[0][1], e1, c0);
            c1 = __builtin_elementwise_fma(W2p[1][1], e1, c1);
            c2 = __builtin_elementwise_fma(W2p[2][1], e1, c2);
            c3 = __builtin_elementwise_fma(W2p[3][1], e1, c3);
            c0 = __builtin_elementwise_fma(W2p[0][2], e2, c0);
            c1 = __builtin_elementwise_fma(W2p[1][2], e2, c1);
            c2 = __builtin_elementwise_fma(W2p[2][2], e2, c2);
            c3 = __builtin_elementwise_fma(W2p[3][2], e2, c3);
            c0 = __builtin_elementwise_fma(W2p[0][3], e3, c0);
            c1 = __builtin_elementwise_fma(W2p[1][3], e3, c1);
            c2 = __builtin_elementwise_fma(W2p[2][3], e3, c2);
            c3 = __builtin_elementwise_fma(W2p[3][3], e3, c3);
            c0 = __builtin_elementwise_fma(W2p[0][4], e4, c0);
            c1 = __builtin_elementwise_fma(W2p[1][4], e4, c1);
            c2 = __builtin_elementwise_fma(W2p[2][4], e4, c2);
            c3 = __builtin_elementwise_fma(W2p[3][4], e4, c3);
            c0 = __builtin_elementwise_fma(W2p[0][5], e5, c0);
            c1 = __builtin_elementwise_fma(W2p[1][5], e5, c1);
            c2 = __builtin_elementwise_fma(W2p[2][5], e5, c2);
            c3 = __builtin_elementwise_fma(W2p[3][5], e5, c3);
            c0 = __builtin_elementwise_fma(W2p[0][6], e6, c0);
            c1 = __builtin_elementwise_fma(W2p[1][6], e6, c1);
            c2 = __builtin_elementwise_fma(W2p[2][6], e6, c2);
            c3 = __builtin_elementwise_fma(W2p[3][6], e6, c3);
            c0 = __builtin_elementwise_fma(W2p[0][7], e7, c0);
            c1 = __builtin_elementwise_fma(W2p[1][7], e7, c1);
            c2 = __builtin_elementwise_fma(W2p[2][7], e7, c2);
            c3 = __builtin_elementwise_fma(W2p[3][7], e7, c3);
            const float P0 = c0.x + c0.y;
            const float P1 = c1.x + c1.y;
            const float P2 = c2.x + c2.y;
            const float P3 = c3.x + c3.y;
            const float Q = P0 + dpp_f<0xB1>(P1) + dpp_f<0x4E>(P2) + dpp_f<0x1B>(P3);
            const float z2 = tanh_fast(Q);
            const unsigned zh_w = (unsigned)(uintptr_t)&zhist[zb4 + li * ZSTR + lane];
            const unsigned zh_r = (unsigned)(uintptr_t)&zhist[zb4 + li * ZSTR + q * 16];
            v4f t0, t1, t2, t3;
            lds_bcast16(zh_w, z2, zh_r, t0, t1, t2, t3);

            v2f f0 = {t0.x, t0.y}, f1 = {t0.z, t0.w};
            v2f f2 = {t1.x, t1.y}, f3 = {t1.z, t1.w};
            v2f f4 = {t2.x, t2.y}, f5 = {t2.z, t2.w};
            v2f f6 = {t3.x, t3.y}, f7 = {t3.z, t3.w};
            v2f m0 = {m3od, 0.f}, m1 = {0.f, 0.f}, m2 = {0.f, 0.f}, m3 = {0.f, 0.f};
            m0 = __builtin_elementwise_fma(Mp[0][0], f0, m0);
            m1 = __builtin_elementwise_fma(Mp[1][0], f0, m1);
            m2 = __builtin_elementwise_fma(Mp[2][0], f0, m2);
            m3 = __builtin_elementwise_fma(Mp[3][0], f0, m3);
            m0 = __builtin_elementwise_fma(Mp[0][1], f1, m0);
            m1 = __builtin_elementwise_fma(Mp[1][1], f1, m1);
            m2 = __builtin_elementwise_fma(Mp[2][1], f1, m2);
            m3 = __builtin_elementwise_fma(Mp[3][1], f1, m3);
            m0 = __builtin_elementwise_fma(Mp[0][2], f2, m0);
            m1 = __builtin_elementwise_fma(Mp[1][2], f2, m1);
            m2 = __builtin_elementwise_fma(Mp[2][2], f2, m2);
            m3 = __builtin_elementwise_fma(Mp[3][2], f2, m3);
            m0 = __builtin_elementwise_fma(Mp[0][3], f3, m0);
            m1 = __builtin_elementwise_fma(Mp[1][3], f3, m1);
            m2 = __builtin_elementwise_fma(Mp[2][3], f3, m2);
            m3 = __builtin_elementwise_fma(Mp[3][3], f3, m3);
            m0 = __builtin_elementwise_fma(Mp[0][4], f4, m0);
            m1 = __builtin_elementwise_fma(Mp[1][4], f4, m1);
            m2 = __builtin_elementwise_fma(Mp[2][4], f4, m2);
            m3 = __builtin_elementwise_fma(Mp[3][4], f4, m3);
            m0 = __builtin_elementwise_fma(Mp[0][5], f5, m0);
            m1 = __builtin_elementwise_fma(Mp[1][5], f5, m1);
            m2 = __builtin_elementwise_fma(Mp[2][5], f5, m2);
            m3 = __builtin_elementwise_fma(Mp[3][5], f5, m3);
            m0 = __builtin_elementwise_fma(Mp[0][6], f6, m0);
            m1 = __builtin_elementwise_fma(Mp[1][6], f6, m1);
            m2 = __builtin_elementwise_fma(Mp[2][6], f6, m2);
            m3 = __builtin_elementwise_fma(Mp[3][6], f6, m3);
            m0 = __builtin_elementwise_fma(Mp[0][7], f7, m0);
            m1 = __builtin_elementwise_fma(Mp[1][7], f7, m1);
            m2 = __builtin_elementwise_fma(Mp[2][7], f7, m2);
            m3 = __builtin_elementwise_fma(Mp[3][7], f7, m3);
            const float R0 = m0.x + m0.y;
            const float R1 = m1.x + m1.y;
            const float R2 = m2.x + m2.y;
            const float R3 = m3.x + m3.y;
            const float R = R0 + dpp_f<0xB1>(R1) + dpp_f<0x4E>(R2) + dpp_f<0x1B>(R3);
            A = fmaf(dt, R, A);
            uacc = uacc_next;
        };

        for (int cb = 0; cb <= NCHUNK; ++cb) {
            while (__hip_atomic_load(&flg[1], __ATOMIC_ACQUIRE,
                                     __HIP_MEMORY_SCOPE_WORKGROUP) < cb + 1)
                __builtin_amdgcn_s_sleep(1);
            while (__hip_atomic_load(&flg[2], __ATOMIC_ACQUIRE,
                                     __HIP_MEMORY_SCOPE_WORKGROUP) < cb - 1)
                __builtin_amdgcn_s_sleep(1);
            const int zb4 = (cb & 1) * ZH;
            const int ub4 = (cb & 1) * UAB;
            if (cb < NCHUNK) {
#pragma unroll 8
                for (int li = 0; li < 64; ++li) step(li, ub4, zb4);
            } else {
                for (int li = 0; li < TAIL; ++li) step(li, ub4, zb4);
            }
            __hip_atomic_store(&flg[0], cb + 1, __ATOMIC_RELEASE,
                               __HIP_MEMORY_SCOPE_WORKGROUP);
        }
    } else {
        // =================== wave 1: staging + uacc + readouts ==============
        float vacc = 0.f;   // per-component z2 sum (for h(T))

        auto uacc_chunk = [&](int c) {
            const int par = (c & 1) * UAB;
            const int src = (c % 3) * 512;
            const int nxt = ((c + 1) % 3) * 512;
            for (int li = 0; li < UROWS; ++li) {
                const int uo = (li < 64) ? src + li * 8 : nxt;
                float4 ua = *(const float4*)&ubuf[uo];
                float4 ub = *(const float4*)&ubuf[uo + 4];
                v2f uv = __builtin_elementwise_fma(W1up[0], (v2f){ua.x, ua.y}, (v2f){0.f, 0.f});
                uv = __builtin_elementwise_fma(W1up[1], (v2f){ua.z, ua.w}, uv);
                uv = __builtin_elementwise_fma(W1up[2], (v2f){ub.x, ub.y}, uv);
                uab[par + li * 64 + lane] = uv.x + uv.y + fmaf(W1u6, ub.z, b1l);
            }
        };
        uacc_chunk(0);
        uacc_chunk(1);
        __hip_atomic_store(&flg[1], 2, __ATOMIC_RELEASE,
                           __HIP_MEMORY_SCOPE_WORKGROUP);

        for (int cb = 0; cb <= NCHUNK; ++cb) {
            while (__hip_atomic_load(&flg[0], __ATOMIC_ACQUIRE,
                                     __HIP_MEMORY_SCOPE_WORKGROUP) < cb + 1)
                __builtin_amdgcn_s_sleep(8);
            if (cb + 3 <= NCHUNK) {
                const int dst = ((cb + 3) % 3) * 512;
                const int base = (cb + 3) * 448;
#pragma unroll
                for (int r = 0; r < UDIM; ++r) {
                    int idx = base + r * 64 + lane;
                    if (idx > T_STEPS * UDIM - 1) idx = T_STEPS * UDIM - 1;
                    const float val = U[idx];
                    int flat = r * 64 + lane;
                    int s = flat / 7, c = flat % 7;
                    ubuf[dst + s * 8 + c] = val;
                }
            }
            if (cb + 2 <= NCHUNK) {
                uacc_chunk(cb + 2);
                __hip_atomic_store(&flg[1], cb + 3, __ATOMIC_RELEASE,
                                   __HIP_MEMORY_SCOPE_WORKGROUP);
            }
            // ---- batched readouts + vacc for chunk cb ----
            const int zb4 = (cb & 1) * ZH;
            const int ns = (cb == NCHUNK) ? TAIL : 64;
            float colsum = 0.f;
            for (int li = 0; li < ns; ++li) colsum += zhist[zb4 + li * ZSTR + lane];
            vacc += colsum;

            const float* zr = &zhist[zb4 + lane * ZSTR];
            v2f sd = {0.f, 0.f}, st = {0.f, 0.f}, sc = {0.f, 0.f};
#pragma unroll
            for (int qq = 0; qq < 32; ++qq) {
                v2f zv = *(const v2f*)&zr[2 * qq];
                sd = __builtin_elementwise_fma(*(const v2f*)&cbuf[2 * qq],       zv, sd);
                st = __builtin_elementwise_fma(*(const v2f*)&cbuf[64 + 2 * qq],  zv, st);
                sc = __builtin_elementwise_fma(*(const v2f*)&cbuf[128 + 2 * qq], zv, sc);
            }
            float Sd = sd.x + sd.y, St = st.x + st.y, Sc = sc.x + sc.y;
            const float oD = Sd, oT = St, oC = Sc;
#pragma unroll
            for (int dl = 1; dl < 64; dl <<= 1) {
                float ud = __shfl_up(Sd, dl, 64);
                float ut = __shfl_up(St, dl, 64);
                float uc = __shfl_up(Sc, dl, 64);
                if (lane >= dl) { Sd += ud; St += ut; Sc += uc; }
            }
            const int t = cb * 64 + lane;
            if (t < T_STEPS) {
                const float fl = (float)lane;
                out[t]               = fmaf(dt, Sd - oD, rchD) + fl * rbD;
                out[T_STEPS + t]     = fmaf(dt, St - oT, rchT) + fl * rbT;
                out[2 * T_STEPS + t] = fmaf(dt, Sc - oC, rchC) + fl * rbC;
            }
            rchD = fmaf(dt, readlane_f(Sd, 63), rchD) + 64.f * rbD;
            rchT = fmaf(dt, readlane_f(St, 63), rchT) + 64.f * rbT;
            rchC = fmaf(dt, readlane_f(Sc, 63), rchC) + 64.f * rbC;
            __hip_atomic_store(&flg[2], cb + 1, __ATOMIC_RELEASE,
                               __HIP_MEMORY_SCOPE_WORKGROUP);
        }

        // ---- h(T) = h0 + dt*W3@vacc + T*dt*b3 (wave0 fully done by now) ----
        zbuf[lane] = vacc;
        if (lane < 16) {
            const float* w3r = W3 + lane * 64;
            float h0a = 0.f, h1a = 0.f;
#pragma unroll
            for (int qq = 0; qq < 16; ++qq) {
                float4 za = *(const float4*)&zbuf[qq * 4];
                h0a = fmaf(w3r[4 * qq + 0], za.x, h0a);
                h1a = fmaf(w3r[4 * qq + 1], za.y, h1a);
                h0a = fmaf(w3r[4 * qq + 2], za.z, h0a);
                h1a = fmaf(w3r[4 * qq + 3], za.w, h1a);
            }
            out[3 * T_STEPS + lane] =
                h0[lane] + dt * (h0a + h1a) + (float)T_STEPS * dt * b3[lane];
        }
    }
}

extern "C" void kernel_launch(void* const* d_in, const int* in_sizes, int n_in,
                              void* d_out, int out_size, void* d_ws, size_t ws_size,
                              hipStream_t stream) {
    const float* U  = (const float*)d_in[0];
    const float* W1 = (const float*)d_in[1];
    const float* b1 = (const float*)d_in[2];
    const float* W2 = (const float*)d_in[3];
    const float* b2 = (const float*)d_in[4];
    const float* W3 = (const float*)d_in[5];
    const float* b3 = (const float*)d_in[6];
    const float* wd = (const float*)d_in[7];
    const float* bd = (const float*)d_in[8];
    const float* wt = (const float*)d_in[9];
    const float* bt = (const float*)d_in[10];
    const float* wc = (const float*)d_in[11];
    const float* bc = (const float*)d_in[12];
    const float* h0 = (const float*)d_in[13];
    (void)in_sizes; (void)n_in; (void)out_size; (void)d_ws; (void)ws_size;

    node_scan<<<dim3(1), dim3(128), 0, stream>>>(U, W1, b1, W2, b2, W3, b3,
                                                 wd, bd, wt, bt, wc, bc, h0,
                                                 (float*)d_out);
}

// Round 8
// 26389.828 us; speedup vs baseline: 1.0795x; 1.0795x over previous
//
#include <hip/hip_runtime.h>

typedef float v2f __attribute__((ext_vector_type(2)));

#define T_STEPS 100000
#define UDIM 7
#define NCHUNK 1562   /* full 64-step chunks */
#define TAIL 32       /* 100000 - 1562*64 */
#define ZSTR 68       /* zhist row stride (floats) */
#define ZH (64 * ZSTR)
#define UROWS 65      /* 64 steps + duplicated row0 of next chunk */
#define UAB (UROWS * 64)

__device__ __forceinline__ float tanh_fast(float x) {
    float e = __expf(2.0f * x);
    return 1.0f - 2.0f * __builtin_amdgcn_rcpf(e + 1.0f);
}

__device__ __forceinline__ float readlane_f(float v, int l) {
    return __int_as_float(__builtin_amdgcn_readlane(__float_as_int(v), l));
}

template <int CTRL>
__device__ __forceinline__ float dpp_f(float v) {
    return __int_as_float(__builtin_amdgcn_update_dpp(
        0, __float_as_int(v), CTRL, 0xF, 0xF, true));
}

__global__ __launch_bounds__(128) __attribute__((amdgpu_waves_per_eu(1, 1)))
void node_scan(const float* __restrict__ U,
               const float* __restrict__ W1, const float* __restrict__ b1,
               const float* __restrict__ W2, const float* __restrict__ b2,
               const float* __restrict__ W3, const float* __restrict__ b3,
               const float* __restrict__ wd, const float* __restrict__ bd,
               const float* __restrict__ wt, const float* __restrict__ bt,
               const float* __restrict__ wc, const float* __restrict__ bc,
               const float* __restrict__ h0,
               float* __restrict__ out)
{
    const int tid  = threadIdx.x;
    const int wv   = tid >> 6;               // 0 = compute wave, 1 = service wave
    const int lane = tid & 63;
    const int g = lane >> 2;                 // output group (0..15)
    const int q = lane & 3;                  // z-segment this lane reads (0..3)
    const float dt = (float)(5.0 / 60.0);

    __shared__ __align__(16) float zbuf[64];          // z1 broadcast / vacc scatter
    __shared__ __align__(16) float ubuf[3 * 512];     // u chunks (wave1-only)
    __shared__ __align__(16) float zhist[2 * ZH];     // z2 history, double-buffered
    __shared__ __align__(16) float cbuf[3 * 64];      // readout functionals (wave1)
    __shared__ __align__(16) float uab[2 * UAB];      // uacc tables, double-buffered
    __shared__ __align__(16) float Msh[64 * 64];      // M staging (init only)
    __shared__ int flg[4];                            // 0=w0 done,1=uacc ready,2=batch done

    if (tid == 0) { flg[0] = 0; flg[1] = 0; flg[2] = 0; }

    // wave0 regs
    float w1h[16]; float b2r = 0.f;
    v2f W2p[4][8];
    // wave1 regs
    v2f W1up[3]; float W1u6 = 0.f, b1l = 0.f;
    float rbD = 0.f, rbT = 0.f, rbC = 0.f, rchD = 0.f, rchT = 0.f, rchC = 0.f;

    if (wv == 0) {
#pragma unroll
        for (int j = 0; j < 16; ++j) w1h[j] = W1[lane * 23 + j];
        b2r = b2[lane];
#pragma unroll
        for (int d = 0; d < 4; ++d) {
            const int orow = (g << 2) | (q ^ d);
            const float* w2r = W2 + orow * 64 + q * 16;
#pragma unroll
            for (int j = 0; j < 8; ++j) W2p[d][j] = (v2f){ w2r[2 * j], w2r[2 * j + 1] };
        }
        for (int c = 0; c < 64; ++c) {
            float acc = 0.f;
#pragma unroll
            for (int k = 0; k < 16; ++k) acc = fmaf(w1h[k], W3[k * 64 + c], acc);
            Msh[lane * 64 + c] = acc;
        }
    } else {
        // u-part weights for this lane's row
#pragma unroll
        for (int j = 0; j < 3; ++j) {
            W1up[j].x = W1[lane * 23 + 16 + 2 * j];
            W1up[j].y = W1[lane * 23 + 17 + 2 * j];
        }
        W1u6 = W1[lane * 23 + 22];
        b1l = b1[lane];
        // readout functionals c = W3^T w → LDS
        float cd = 0.f, ct = 0.f, cc = 0.f;
        for (int k = 0; k < 16; ++k) {
            const float w3v = W3[k * 64 + lane];
            cd = fmaf(wd[k], w3v, cd);
            ct = fmaf(wt[k], w3v, ct);
            cc = fmaf(wc[k], w3v, cc);
        }
        cbuf[lane] = cd; cbuf[64 + lane] = ct; cbuf[128 + lane] = cc;
        rchD = bd[0]; rchT = bt[0]; rchC = bc[0];
        for (int k = 0; k < 16; ++k) {
            rbD = fmaf(wd[k], b3[k], rbD);  rchD = fmaf(wd[k], h0[k], rchD);
            rbT = fmaf(wt[k], b3[k], rbT);  rchT = fmaf(wt[k], h0[k], rchT);
            rbC = fmaf(wc[k], b3[k], rbC);  rchC = fmaf(wc[k], h0[k], rchC);
        }
        rbD *= dt; rbT *= dt; rbC *= dt;
        // stage u chunks 0,1,2
#pragma unroll
        for (int c = 0; c < 3; ++c) {
            const int base = c * 448, dst = c * 512;
#pragma unroll
            for (int r = 0; r < UDIM; ++r) {
                int flat = r * 64 + lane;
                int s = flat / 7, cc2 = flat % 7;
                ubuf[dst + s * 8 + cc2] = U[base + flat];
            }
            ubuf[dst + lane * 8 + 7] = 0.f;
        }
    }
    __syncthreads();

    if (wv == 0) {
        v2f Mp[4][8];
#pragma unroll
        for (int d = 0; d < 4; ++d) {
            const int orow = (g << 2) | (q ^ d);
            const float* mr = Msh + orow * 64 + q * 16;
#pragma unroll
            for (int j = 0; j < 8; ++j) Mp[d][j] = (v2f){ mr[2 * j], mr[2 * j + 1] };
        }
        float m3od = 0.f;
#pragma unroll
        for (int k = 0; k < 16; ++k) m3od = fmaf(w1h[k], b3[k], m3od);
        float A = 0.f;
        for (int k = 0; k < 16; ++k) A = fmaf(w1h[k], h0[k], A);

        while (__hip_atomic_load(&flg[1], __ATOMIC_ACQUIRE,
                                 __HIP_MEMORY_SCOPE_WORKGROUP) < 1)
            __builtin_amdgcn_s_sleep(1);
        float uacc = uab[lane];                        // chunk0 row0

        auto step = [&](int li, int ub4, int zb4) {
            const float z1 = tanh_fast(A + uacc);
            zbuf[lane] = z1;
            float4 s0 = *(const float4*)&zbuf[q * 16 + 0];
            float4 s1 = *(const float4*)&zbuf[q * 16 + 4];
            float4 s2 = *(const float4*)&zbuf[q * 16 + 8];
            float4 s3 = *(const float4*)&zbuf[q * 16 + 12];
            const float uacc_next = uab[ub4 + (li + 1) * 64 + lane];

            v2f e0 = {s0.x, s0.y}, e1 = {s0.z, s0.w};
            v2f e2 = {s1.x, s1.y}, e3 = {s1.z, s1.w};
            v2f e4 = {s2.x, s2.y}, e5 = {s2.z, s2.w};
            v2f e6 = {s3.x, s3.y}, e7 = {s3.z, s3.w};
            v2f c0 = {b2r, 0.f}, c1 = {0.f, 0.f}, c2 = {0.f, 0.f}, c3 = {0.f, 0.f};
            c0 = __builtin_elementwise_fma(W2p[0][0], e0, c0);
            c1 = __builtin_elementwise_fma(W2p[1][0], e0, c1);
            c2 = __builtin_elementwise_fma(W2p[2][0], e0, c2);
            c3 = __builtin_elementwise_fma(W2p[3][0], e0, c3);
            c0 = __builtin_elementwise_fma(W2p[0][1], e1, c0);
            c1 = __builtin_elementwise_fma(W2p[1][1], e1, c1);
            c2 = __builtin_elementwise_fma(W2p[2][1], e1, c2);
            c3 = __builtin_elementwise_fma(W2p[3][1], e1, c3);
            c0 = __builtin_elementwise_fma(W2p[0][2], e2, c0);
            c1 = __builtin_elementwise_fma(W2p[1][2], e2, c1);
            c2 = __builtin_elementwise_fma(W2p[2][2], e2, c2);
            c3 = __builtin_elementwise_fma(W2p[3][2], e2, c3);
            c0 = __builtin_elementwise_fma(W2p[0][3], e3, c0);
            c1 = __builtin_elementwise_fma(W2p[1][3], e3, c1);
            c2 = __builtin_elementwise_fma(W2p[2][3], e3, c2);
            c3 = __builtin_elementwise_fma(W2p[3][3], e3, c3);
            c0 = __builtin_elementwise_fma(W2p[0][4], e4, c0);
            c1 = __builtin_elementwise_fma(W2p[1][4], e4, c1);
            c2 = __builtin_elementwise_fma(W2p[2][4], e4, c2);
            c3 = __builtin_elementwise_fma(W2p[3][4], e4, c3);
            c0 = __builtin_elementwise_fma(W2p[0][5], e5, c0);
            c1 = __builtin_elementwise_fma(W2p[1][5], e5, c1);
            c2 = __builtin_elementwise_fma(W2p[2][5], e5, c2);
            c3 = __builtin_elementwise_fma(W2p[3][5], e5, c3);
            c0 = __builtin_elementwise_fma(W2p[0][6], e6, c0);
            c1 = __builtin_elementwise_fma(W2p[1][6], e6, c1);
            c2 = __builtin_elementwise_fma(W2p[2][6], e6, c2);
            c3 = __builtin_elementwise_fma(W2p[3][6], e6, c3);
            c0 = __builtin_elementwise_fma(W2p[0][7], e7, c0);
            c1 = __builtin_elementwise_fma(W2p[1][7], e7, c1);
            c2 = __builtin_elementwise_fma(W2p[2][7], e7, c2);
            c3 = __builtin_elementwise_fma(W2p[3][7], e7, c3);
            const float P0 = c0.x + c0.y;
            const float P1 = c1.x + c1.y;
            const float P2 = c2.x + c2.y;
            const float P3 = c3.x + c3.y;
            const float Q = P0 + dpp_f<0xB1>(P1) + dpp_f<0x4E>(P2) + dpp_f<0x1B>(P3);
            const float z2 = tanh_fast(Q);
            zhist[zb4 + li * ZSTR + lane] = z2;
            const float* zrow = &zhist[zb4 + li * ZSTR + q * 16];
            float4 t0 = *(const float4*)&zrow[0];
            float4 t1 = *(const float4*)&zrow[4];
            float4 t2 = *(const float4*)&zrow[8];
            float4 t3 = *(const float4*)&zrow[12];

            v2f f0 = {t0.x, t0.y}, f1 = {t0.z, t0.w};
            v2f f2 = {t1.x, t1.y}, f3 = {t1.z, t1.w};
            v2f f4 = {t2.x, t2.y}, f5 = {t2.z, t2.w};
            v2f f6 = {t3.x, t3.y}, f7 = {t3.z, t3.w};
            v2f m0 = {m3od, 0.f}, m1 = {0.f, 0.f}, m2 = {0.f, 0.f}, m3 = {0.f, 0.f};
            m0 = __builtin_elementwise_fma(Mp[0][0], f0, m0);
            m1 = __builtin_elementwise_fma(Mp[1][0], f0, m1);
            m2 = __builtin_elementwise_fma(Mp[2][0], f0, m2);
            m3 = __builtin_elementwise_fma(Mp[3][0], f0, m3);
            m0 = __builtin_elementwise_fma(Mp[0][1], f1, m0);
            m1 = __builtin_elementwise_fma(Mp[1][1], f1, m1);
            m2 = __builtin_elementwise_fma(Mp[2][1], f1, m2);
            m3 = __builtin_elementwise_fma(Mp[3][1], f1, m3);
            m0 = __builtin_elementwise_fma(Mp[0][2], f2, m0);
            m1 = __builtin_elementwise_fma(Mp[1][2], f2, m1);
            m2 = __builtin_elementwise_fma(Mp[2][2], f2, m2);
            m3 = __builtin_elementwise_fma(Mp[3][2], f2, m3);
            m0 = __builtin_elementwise_fma(Mp[0][3], f3, m0);
            m1 = __builtin_elementwise_fma(Mp[1][3], f3, m1);
            m2 = __builtin_elementwise_fma(Mp[2][3], f3, m2);
            m3 = __builtin_elementwise_fma(Mp[3][3], f3, m3);
            m0 = __builtin_elementwise_fma(Mp[0][4], f4, m0);
            m1 = __builtin_elementwise_fma(Mp[1][4], f4, m1);
            m2 = __builtin_elementwise_fma(Mp[2][4], f4, m2);
            m3 = __builtin_elementwise_fma(Mp[3][4], f4, m3);
            m0 = __builtin_elementwise_fma(Mp[0][5], f5, m0);
            m1 = __builtin_elementwise_fma(Mp[1][5], f5, m1);
            m2 = __builtin_elementwise_fma(Mp[2][5], f5, m2);
            m3 = __builtin_elementwise_fma(Mp[3][5], f5, m3);
            m0 = __builtin_elementwise_fma(Mp[0][6], f6, m0);
            m1 = __builtin_elementwise_fma(Mp[1][6], f6, m1);
            m2 = __builtin_elementwise_fma(Mp[2][6], f6, m2);
            m3 = __builtin_elementwise_fma(Mp[3][6], f6, m3);
            m0 = __builtin_elementwise_fma(Mp[0][7], f7, m0);
            m1 = __builtin_elementwise_fma(Mp[1][7], f7, m1);
            m2 = __builtin_elementwise_fma(Mp[2][7], f7, m2);
            m3 = __builtin_elementwise_fma(Mp[3][7], f7, m3);
            const float R0 = m0.x + m0.y;
            const float R1 = m1.x + m1.y;
            const float R2 = m2.x + m2.y;
            const float R3 = m3.x + m3.y;
            const float R = R0 + dpp_f<0xB1>(R1) + dpp_f<0x4E>(R2) + dpp_f<0x1B>(R3);
            A = fmaf(dt, R, A);
            uacc = uacc_next;
        };

        for (int cb = 0; cb <= NCHUNK; ++cb) {
            while (__hip_atomic_load(&flg[1], __ATOMIC_ACQUIRE,
                                     __HIP_MEMORY_SCOPE_WORKGROUP) < cb + 1)
                __builtin_amdgcn_s_sleep(1);
            while (__hip_atomic_load(&flg[2], __ATOMIC_ACQUIRE,
                                     __HIP_MEMORY_SCOPE_WORKGROUP) < cb - 1)
                __builtin_amdgcn_s_sleep(1);
            const int zb4 = (cb & 1) * ZH;
            const int ub4 = (cb & 1) * UAB;
            if (cb < NCHUNK) {
#pragma unroll 8
                for (int li = 0; li < 64; ++li) step(li, ub4, zb4);
            } else {
                for (int li = 0; li < TAIL; ++li) step(li, ub4, zb4);
            }
            __hip_atomic_store(&flg[0], cb + 1, __ATOMIC_RELEASE,
                               __HIP_MEMORY_SCOPE_WORKGROUP);
        }
    } else {
        // =================== wave 1: staging + uacc + readouts ==============
        float vacc = 0.f;   // per-component z2 sum (for h(T))

        auto uacc_chunk = [&](int c) {
            const int par = (c & 1) * UAB;
            const int src = (c % 3) * 512;
            const int nxt = ((c + 1) % 3) * 512;
            for (int li = 0; li < UROWS; ++li) {
                const int uo = (li < 64) ? src + li * 8 : nxt;
                float4 ua = *(const float4*)&ubuf[uo];
                float4 ub = *(const float4*)&ubuf[uo + 4];
                v2f uv = __builtin_elementwise_fma(W1up[0], (v2f){ua.x, ua.y}, (v2f){0.f, 0.f});
                uv = __builtin_elementwise_fma(W1up[1], (v2f){ua.z, ua.w}, uv);
                uv = __builtin_elementwise_fma(W1up[2], (v2f){ub.x, ub.y}, uv);
                uab[par + li * 64 + lane] = uv.x + uv.y + fmaf(W1u6, ub.z, b1l);
            }
        };
        uacc_chunk(0);
        uacc_chunk(1);
        __hip_atomic_store(&flg[1], 2, __ATOMIC_RELEASE,
                           __HIP_MEMORY_SCOPE_WORKGROUP);

        for (int cb = 0; cb <= NCHUNK; ++cb) {
            while (__hip_atomic_load(&flg[0], __ATOMIC_ACQUIRE,
                                     __HIP_MEMORY_SCOPE_WORKGROUP) < cb + 1)
                __builtin_amdgcn_s_sleep(8);
            if (cb + 3 <= NCHUNK) {
                const int dst = ((cb + 3) % 3) * 512;
                const int base = (cb + 3) * 448;
#pragma unroll
                for (int r = 0; r < UDIM; ++r) {
                    int idx = base + r * 64 + lane;
                    if (idx > T_STEPS * UDIM - 1) idx = T_STEPS * UDIM - 1;
                    const float val = U[idx];
                    int flat = r * 64 + lane;
                    int s = flat / 7, c = flat % 7;
                    ubuf[dst + s * 8 + c] = val;
                }
            }
            if (cb + 2 <= NCHUNK) {
                uacc_chunk(cb + 2);
                __hip_atomic_store(&flg[1], cb + 3, __ATOMIC_RELEASE,
                                   __HIP_MEMORY_SCOPE_WORKGROUP);
            }
            // ---- batched readouts + vacc for chunk cb ----
            const int zb4 = (cb & 1) * ZH;
            const int ns = (cb == NCHUNK) ? TAIL : 64;
            float colsum = 0.f;
            for (int li = 0; li < ns; ++li) colsum += zhist[zb4 + li * ZSTR + lane];
            vacc += colsum;

            const float* zr = &zhist[zb4 + lane * ZSTR];
            v2f sd = {0.f, 0.f}, st = {0.f, 0.f}, sc = {0.f, 0.f};
#pragma unroll
            for (int qq = 0; qq < 32; ++qq) {
                v2f zv = *(const v2f*)&zr[2 * qq];
                sd = __builtin_elementwise_fma(*(const v2f*)&cbuf[2 * qq],       zv, sd);
                st = __builtin_elementwise_fma(*(const v2f*)&cbuf[64 + 2 * qq],  zv, st);
                sc = __builtin_elementwise_fma(*(const v2f*)&cbuf[128 + 2 * qq], zv, sc);
            }
            float Sd = sd.x + sd.y, St = st.x + st.y, Sc = sc.x + sc.y;
            const float oD = Sd, oT = St, oC = Sc;
#pragma unroll
            for (int dl = 1; dl < 64; dl <<= 1) {
                float ud = __shfl_up(Sd, dl, 64);
                float ut = __shfl_up(St, dl, 64);
                float uc = __shfl_up(Sc, dl, 64);
                if (lane >= dl) { Sd += ud; St += ut; Sc += uc; }
            }
            const int t = cb * 64 + lane;
            if (t < T_STEPS) {
                const float fl = (float)lane;
                out[t]               = fmaf(dt, Sd - oD, rchD) + fl * rbD;
                out[T_STEPS + t]     = fmaf(dt, St - oT, rchT) + fl * rbT;
                out[2 * T_STEPS + t] = fmaf(dt, Sc - oC, rchC) + fl * rbC;
            }
            rchD = fmaf(dt, readlane_f(Sd, 63), rchD) + 64.f * rbD;
            rchT = fmaf(dt, readlane_f(St, 63), rchT) + 64.f * rbT;
            rchC = fmaf(dt, readlane_f(Sc, 63), rchC) + 64.f * rbC;
            __hip_atomic_store(&flg[2], cb + 1, __ATOMIC_RELEASE,
                               __HIP_MEMORY_SCOPE_WORKGROUP);
        }

        // ---- h(T) = h0 + dt*W3@vacc + T*dt*b3 (wave0 fully done by now) ----
        zbuf[lane] = vacc;
        if (lane < 16) {
            const float* w3r = W3 + lane * 64;
            float h0a = 0.f, h1a = 0.f;
#pragma unroll
            for (int qq = 0; qq < 16; ++qq) {
                float4 za = *(const float4*)&zbuf[qq * 4];
                h0a = fmaf(w3r[4 * qq + 0], za.x, h0a);
                h1a = fmaf(w3r[4 * qq + 1], za.y, h1a);
                h0a = fmaf(w3r[4 * qq + 2], za.z, h0a);
                h1a = fmaf(w3r[4 * qq + 3], za.w, h1a);
            }
            out[3 * T_STEPS + lane] =
                h0[lane] + dt * (h0a + h1a) + (float)T_STEPS * dt * b3[lane];
        }
    }
}

extern "C" void kernel_launch(void* const* d_in, const int* in_sizes, int n_in,
                              void* d_out, int out_size, void* d_ws, size_t ws_size,
                              hipStream_t stream) {
    const float* U  = (const float*)d_in[0];
    const float* W1 = (const float*)d_in[1];
    const float* b1 = (const float*)d_in[2];
    const float* W2 = (const float*)d_in[3];
    const float* b2 = (const float*)d_in[4];
    const float* W3 = (const float*)d_in[5];
    const float* b3 = (const float*)d_in[6];
    const float* wd = (const float*)d_in[7];
    const float* bd = (const float*)d_in[8];
    const float* wt = (const float*)d_in[9];
    const float* bt = (const float*)d_in[10];
    const float* wc = (const float*)d_in[11];
    const float* bc = (const float*)d_in[12];
    const float* h0 = (const float*)d_in[13];
    (void)in_sizes; (void)n_in; (void)out_size; (void)d_ws; (void)ws_size;

    node_scan<<<dim3(1), dim3(128), 0, stream>>>(U, W1, b1, W2, b2, W3, b3,
                                                 wd, bd, wt, bt, wc, bc, h0,
                                                 (float*)d_out);
}